// Round 1
// baseline (97.357 us; speedup 1.0000x reference)
//
#include <hip/hip_runtime.h>

// RandomHingeFern: B=4096, C_in=512, O=1024, D=10, L=2^10=1024
// out[b,o] = weights[o, leaf(b,o)] * min_d |x[b, ord[o,d]] - thr[o,d]|
// leaf = sum_d (x[b,ord[o,d]] > thr[o,d]) << (D-1-d)

#define B_TOT   4096
#define CIN     512
#define O_TOT   1024
#define DEPTH   10
#define LEAVES  1024
#define OTILE   256
#define PAD     11   // stride-11 LDS layout: 11*dt % 32 != 0 for dt<32 -> only free 2-way aliasing

__global__ __launch_bounds__(256, 2) void fern_kernel(
    const float* __restrict__ x,          // [B, CIN]
    const float* __restrict__ thresholds, // [O, DEPTH]
    const int*   __restrict__ ordinals,   // [O, DEPTH]
    const float* __restrict__ weights,    // [O, LEAVES]
    float*       __restrict__ out)        // [B, O]
{
    __shared__ float xrow[CIN];
    __shared__ int   s_ord[OTILE * PAD];
    __shared__ float s_thr[OTILE * PAD];

    const int t  = threadIdx.x;           // 0..255
    const int b  = blockIdx.x;            // 0..4095
    const int o0 = blockIdx.y * OTILE;    // 0, 256, 512, 768

    // Stage x[b, :] into LDS — coalesced float2 (256 threads x 8B = 2KB)
    const float2 xv = reinterpret_cast<const float2*>(x + (size_t)b * CIN)[t];
    reinterpret_cast<float2*>(xrow)[t] = xv;

    // Stage this o-tile's ordinals/thresholds — coalesced global reads,
    // written to padded [OTILE][PAD] layout.
    const int gbase = o0 * DEPTH;
#pragma unroll
    for (int k = 0; k < DEPTH; ++k) {
        const int j = k * OTILE + t;          // 0..2559, coalesced
        const int oo = j / DEPTH;
        const int dd = j - oo * DEPTH;
        s_ord[oo * PAD + dd] = ordinals[gbase + j];
        s_thr[oo * PAD + dd] = thresholds[gbase + j];
    }
    __syncthreads();

    const int o = o0 + t;
    int   leaf = 0;
    float mm   = 1e30f;
#pragma unroll
    for (int d = 0; d < DEPTH; ++d) {
        const int   ord    = s_ord[t * PAD + d];
        const float thr    = s_thr[t * PAD + d];
        const float margin = xrow[ord] - thr;
        leaf = (leaf << 1) | (margin > 0.0f ? 1 : 0);
        mm   = fminf(mm, fabsf(margin));
    }

    const float w = weights[(size_t)o * LEAVES + leaf];
    out[(size_t)b * O_TOT + o] = w * mm;
}

extern "C" void kernel_launch(void* const* d_in, const int* in_sizes, int n_in,
                              void* d_out, int out_size, void* d_ws, size_t ws_size,
                              hipStream_t stream) {
    const float* x          = (const float*)d_in[0];
    const float* thresholds = (const float*)d_in[1];
    const int*   ordinals   = (const int*)d_in[2];
    const float* weights    = (const float*)d_in[3];
    float*       out        = (float*)d_out;

    dim3 grid(B_TOT, O_TOT / OTILE);   // 4096 x 4
    fern_kernel<<<grid, OTILE, 0, stream>>>(x, thresholds, ordinals, weights, out);
}

// Round 2
// 88.261 us; speedup vs baseline: 1.1031x; 1.1031x over previous
//
#include <hip/hip_runtime.h>

// RandomHingeFern: B=4096, C_in=512, O=1024, D=10, L=2^10=1024
// out[b,o] = weights[o, leaf(b,o)] * min_d |x[b, ord[o,d]] - thr[o,d]|
// leaf = sum_d (x[b,ord[o,d]] > thr[o,d]) << (D-1-d)

#define B_TOT   4096
#define CIN     512
#define O_TOT   1024
#define DEPTH   10
#define LEAVES  1024
#define OTILE   256
#define BTILE   8
#define PAD     11   // stride-11: (11*t+d)%32 covers all banks, only free 2-way aliasing

__global__ __launch_bounds__(256, 4) void fern_kernel(
    const float* __restrict__ x,          // [B, CIN]
    const float* __restrict__ thresholds, // [O, DEPTH]
    const int*   __restrict__ ordinals,   // [O, DEPTH]
    const float* __restrict__ weights,    // [O, LEAVES]
    float*       __restrict__ out)        // [B, O]
{
    __shared__ float xt[BTILE][CIN];      // 16 KB
    __shared__ int   s_ord[OTILE * PAD];  // 11.25 KB
    __shared__ float s_thr[OTILE * PAD];  // 11.25 KB

    const int t  = threadIdx.x;               // 0..255
    const int b0 = blockIdx.x * BTILE;        // sample tile base
    const int o0 = blockIdx.y * OTILE;        // fern tile base

    // Stage 8 x-rows (16 KB) as float4 — fully coalesced.
    // 8 rows x 128 float4 = 1024 float4; thread does 4.
#pragma unroll
    for (int k = 0; k < 4; ++k) {
        const int idx = k * 256 + t;          // 0..1023
        const int row = idx >> 7;             // /128
        const int col = (idx & 127) << 2;     // float index, 16B aligned
        const float4 v = *reinterpret_cast<const float4*>(
            x + (size_t)(b0 + row) * CIN + col);
        *reinterpret_cast<float4*>(&xt[row][col]) = v;
    }

    // Stage this o-tile's ordinals/thresholds — coalesced, padded layout.
    const int gbase = o0 * DEPTH;
#pragma unroll
    for (int k = 0; k < DEPTH; ++k) {
        const int j  = k * OTILE + t;         // 0..2559, coalesced
        const int oo = j / DEPTH;
        const int dd = j - oo * DEPTH;
        s_ord[oo * PAD + dd] = ordinals[gbase + j];
        s_thr[oo * PAD + dd] = thresholds[gbase + j];
    }
    __syncthreads();

    // Pull my fern's params into registers ONCE (contiguous -> b128 reads).
    int   ordr[DEPTH];
    float thrr[DEPTH];
#pragma unroll
    for (int d = 0; d < DEPTH; ++d) {
        ordr[d] = s_ord[t * PAD + d];
        thrr[d] = s_thr[t * PAD + d];
    }

    const int o = o0 + t;
    const float* __restrict__ wrow = weights + (size_t)o * LEAVES;

#pragma unroll
    for (int bb = 0; bb < BTILE; ++bb) {
        int   leaf = 0;
        float mm   = 1e30f;
#pragma unroll
        for (int d = 0; d < DEPTH; ++d) {
            const float margin = xt[bb][ordr[d]] - thrr[d];
            leaf = (leaf << 1) | (margin > 0.0f ? 1 : 0);
            mm   = fminf(mm, fabsf(margin));
        }
        const float w = wrow[leaf];
        // Streaming store: keep L2 for weights/x, not the write-once output.
        __builtin_nontemporal_store(w * mm, out + (size_t)(b0 + bb) * O_TOT + o);
    }
}

extern "C" void kernel_launch(void* const* d_in, const int* in_sizes, int n_in,
                              void* d_out, int out_size, void* d_ws, size_t ws_size,
                              hipStream_t stream) {
    const float* x          = (const float*)d_in[0];
    const float* thresholds = (const float*)d_in[1];
    const int*   ordinals   = (const int*)d_in[2];
    const float* weights    = (const float*)d_in[3];
    float*       out        = (float*)d_out;

    dim3 grid(B_TOT / BTILE, O_TOT / OTILE);   // 512 x 4
    fern_kernel<<<grid, 256, 0, stream>>>(x, thresholds, ordinals, weights, out);
}